// Round 14
// baseline (113.744 us; speedup 1.0000x reference)
//
#include <hip/hip_runtime.h>

#define MDIM 512
#define LCH  31
#define CDIM 542   // MD + L - 1
#define INW  1024
#define RS   (INW*LCH)          // floats per input row = 31744
#define NELEM (MDIM*MDIM*LCH)   // 8126464
#define GB3  2048               // k3/k4 grid blocks

#define TNK  32                 // output n-cols per k1 tile
#define NT   16                 // tiles per row (512/32)
#define NPAIR 256               // m-pairs
#define SEG  2048               // staged floats per row slot

// ws layout (floats): part[pair][tile][mm][128], yn, pmaxY[512], pmaxT[GB3]
#define PART_OFF 0
#define PART_SZ  (NPAIR*NT*2*128)        // 1048576
#define YN_OFF   (PART_OFF + PART_SZ)
#define PMY_OFF  (YN_OFF + MDIM*CDIM)
#define PMT_OFF  (PMY_OFF + MDIM)

typedef const __attribute__((address_space(1))) void* gas_ptr;
typedef __attribute__((address_space(3))) void* las_ptr;
__device__ __forceinline__ void gload16(const float* g, float* l) {
    __builtin_amdgcn_global_load_lds((gas_ptr)g, (las_ptr)l, 16, 0, 0);
}

// K1: r9 math, load path replaced by global_load_lds staging.
// Block = (m-pair p, n-tile of 32). 6 raw X rows (48 KB) staged direct to
// LDS — zero VGPR pressure (register-staged loads were re-serialized by the
// compiler at VGPR<=40 in r5/r6/r8/r12). One __syncthreads drains the stage.
// H tile prefetched into 8 regs BEFORE the drain so its latency hides.
// r13 BUG FIX: H prefetch must use stride MDIM*LCH between the pair's rows
// (r13 loaded flat [0,2048) -> wrong H for mm=1, absmax 0.37).
// Clamped values only meet zero weights:
//   col -1 / 1024 -> wx0/wx3 = 0 at n = 0/511
//   row -1 / 1024 -> wa0/wb3 = 0 at m = 0/511
__global__ __launch_bounds__(256) void k1_fused(const float* __restrict__ X,
                                                const float* __restrict__ H,
                                                float* __restrict__ part) {
    __shared__ float rows[6][SEG];    // 49.2 KB raw X row segments
    __shared__ float xv[2][SEG];      // 16.4 KB vertically-resized tiles
    __shared__ float xm[2][32][33];   // 8.4 KB H*conv tiles, padded

    const int bid  = blockIdx.x;
    const int t    = bid & (NT-1);
    const int p    = bid >> 4;
    const int n0   = t * TNK;
    const int m0   = 2*p;
    const int tid  = threadIdx.x;
    const int wave = tid >> 6;
    const int lane = tid & 63;
    const int qa   = 1984*t - 32;     // float4-aligned staged-q origin (mod4==0)

    // ---- stage: 6 rows x 8 chunks of 1 KB, direct global->LDS ----
    for (int i = wave; i < 48; i += 4) {
        const int r = i >> 3, c = i & 7;
        const int u = (c << 6) + lane;                    // float4 idx in [0,512)
        const int q = min(max(qa + 4*u, 0), RS - 4);      // clamp -> zero-weight
        const float* src = X + (size_t)min(max(4*p - 1 + r, 0), INW-1)*RS + q;
        gload16(src, &rows[r][c << 8]);
    }

    // H prefetch into registers (overlaps the stage drain).
    // Slot k serves phase-2 element idx = tid + k*256: H index is
    // hbase + mm*MDIM*LCH + r2 (NOT flat idx — that was the r13 bug).
    const size_t hbase = ((size_t)m0*MDIM + n0)*LCH;
    float harr[8];
    #pragma unroll
    for (int k = 0; k < 8; ++k) {
        int idx = tid + (k << 8);
        if (idx >= 2*TNK*LCH) idx = 2*TNK*LCH - 1;        // unused tail, clamp
        const int mm = idx >= TNK*LCH;
        const int r2 = mm ? idx - TNK*LCH : idx;
        harr[k] = H[hbase + (size_t)mm*(MDIM*LCH) + r2];
    }
    __syncthreads();   // vmcnt(0) drain + barrier: rows[] ready

    // ---- phase A: vertical 4-tap (LDS rows -> LDS xv), float4 granular ----
    float wa0=0.125f, wa1=0.375f, wa2=0.375f, wa3=0.125f;   // m = m0
    if (m0 == 0) {
        const float s = 1.0f/0.875f;
        wa0 = 0.f; wa1 = 0.375f*s; wa2 = 0.375f*s; wa3 = 0.125f*s;
    }
    float wb0=0.125f, wb1=0.375f, wb2=0.375f, wb3=0.125f;   // m = m0+1
    if (m0 + 1 == MDIM-1) {
        const float s = 1.0f/0.875f;
        wb0 = 0.125f*s; wb1 = 0.375f*s; wb2 = 0.375f*s; wb3 = 0.f;
    }
    #pragma unroll
    for (int j = 0; j < 4; ++j) {
        const int u4 = tid + (j << 8);        // [0,1024)
        const int mm = u4 >> 9;
        const int uu = u4 & 511;              // float4 index within tile
        const float4 r0 = *(const float4*)&rows[2*mm + 0][4*uu];
        const float4 r1 = *(const float4*)&rows[2*mm + 1][4*uu];
        const float4 r2 = *(const float4*)&rows[2*mm + 2][4*uu];
        const float4 r3 = *(const float4*)&rows[2*mm + 3][4*uu];
        const float w0 = mm ? wb0 : wa0, w1 = mm ? wb1 : wa1;
        const float w2 = mm ? wb2 : wa2, w3 = mm ? wb3 : wa3;
        float4 v;
        v.x = fmaf(w0,r0.x, fmaf(w1,r1.x, fmaf(w2,r2.x, w3*r3.x)));
        v.y = fmaf(w0,r0.y, fmaf(w1,r1.y, fmaf(w2,r2.y, w3*r3.y)));
        v.z = fmaf(w0,r0.z, fmaf(w1,r1.z, fmaf(w2,r2.z, w3*r3.z)));
        v.w = fmaf(w0,r0.w, fmaf(w1,r1.w, fmaf(w2,r2.w, w3*r3.w)));
        *(float4*)&xv[mm][4*uu] = v;
    }
    __syncthreads();

    // ---- phase 2: l-conv + horizontal 4-tap + H multiply -> xm tile ----
    // xv[mm][i] holds vert(q = qa + i); tap (col = 2n-1+b, l) at
    // i = 2*nl*31 + 31*b + l + 1 (max 2046 < 2048).
    #pragma unroll
    for (int k = 0; k < 8; ++k) {
        const int idx = tid + (k << 8);
        if (idx < 2*TNK*LCH) {                // 1984
            const int mm = idx >= TNK*LCH;
            const int r2 = mm ? idx - TNK*LCH : idx;
            const int nl = r2 / 31;
            const int l  = r2 - nl*31;
            const int n  = n0 + nl;
            float wx0=0.125f, wx1=0.375f, wx2=0.375f, wx3=0.125f;
            if (n == 0)      wx0 = 0.f;
            if (n == MDIM-1) wx3 = 0.f;
            if (n == 0 || n == MDIM-1) {
                const float s = 1.0f/0.875f;
                wx0*=s; wx1*=s; wx2*=s; wx3*=s;
            }
            const float wb4[4] = {wx0, wx1, wx2, wx3};
            const float* xvm = xv[mm];
            const int ib = 2*nl*31 + l + 1;
            float acc = 0.f;
            #pragma unroll
            for (int b = 0; b < 4; ++b) {
                const float* q = xvm + ib + 31*b;
                float c = 0.5f*q[0];
                if (l > 0)  c += 0.25f*q[-1];
                if (l < 30) c += 0.25f*q[1];
                acc = fmaf(wb4[b], c, acc);
            }
            xm[mm][nl][l] = acc * harr[k];
        }
    }
    __syncthreads();

    // ---- phase 3: diagonal partials: cl = c - n0 in [0,62), 2 halves ----
    if (tid < 248) {
        const int mm = tid >= 124;
        const int r3 = mm ? tid - 124 : tid;
        const int h  = r3 >= 62;
        const int cl = h ? r3 - 62 : r3;
        const int ilo = max(0, cl - (TNK-1));
        const int ihi = min(30, cl);
        const int mid = (ilo + ihi + 1) >> 1;
        const int lo  = h ? mid : ilo;
        const int hi  = h ? ihi : mid - 1;
        float s = 0.f;
        for (int i = lo; i <= hi; ++i)
            s += xm[mm][cl - i][i];          // stride-33 -> conflict-free
        part[(((size_t)p*NT + t)*2 + mm)*128 + h*64 + cl] = s;
    }
}

// K2_lite: yn[m][c] = sum of <=2 tile-partials x 2 halves; per-row max.
__global__ __launch_bounds__(256) void k2_lite(const float* __restrict__ part,
                                               float* __restrict__ yn,
                                               float* __restrict__ pmaxY) {
    const int m = blockIdx.x;
    const int p = m >> 1, mm = m & 1;
    float lmax = -3.4e38f;
    for (int c = threadIdx.x; c < CDIM; c += 256) {
        float s = 0.f;
        const int tlo = max(0, (c - 30) >> 5);
        const int thi = min(NT - 1, c >> 5);
        for (int t = tlo; t <= thi; ++t) {
            const int cl = c - TNK*t;               // in [0,62)
            const float* pp = part + (((size_t)p*NT + t)*2 + mm)*128;
            s += pp[cl] + pp[64 + cl];
        }
        yn[m*CDIM + c] = s;
        lmax = fmaxf(lmax, s);
    }
    __shared__ float red[256];
    red[threadIdx.x] = lmax; __syncthreads();
    for (int s = 128; s > 0; s >>= 1) {
        if ((int)threadIdx.x < s)
            red[threadIdx.x] = fmaxf(red[threadIdx.x], red[threadIdx.x+s]);
        __syncthreads();
    }
    if (threadIdx.x == 0) pmaxY[m] = red[0];
}

// block-uniform reduction of an L2-resident partial-max array (deterministic:
// every block computes the identical max; order-free).
__device__ __forceinline__ float block_max_of(const float* __restrict__ arr,
                                              int n, float* red) {
    float lm = -3.4e38f;
    for (int i = threadIdx.x; i < n; i += 256)
        lm = fmaxf(lm, arr[i]);
    __syncthreads();
    red[threadIdx.x] = lm; __syncthreads();
    for (int s = 128; s > 0; s >>= 1) {
        if ((int)threadIdx.x < s)
            red[threadIdx.x] = fmaxf(red[threadIdx.x], red[threadIdx.x+s]);
        __syncthreads();
    }
    return red[0];
}

// t(idx) = H[idx] * conv_i(yn/My - y at c=n+i)
__device__ __forceinline__ float t_elem(int idx,
                                        const float* __restrict__ yn,
                                        const float* __restrict__ y,
                                        const float* __restrict__ H,
                                        float inv) {
    const int i    = idx % LCH;
    const int rest = idx / LCH;
    const int n    = rest & (MDIM-1);
    const int m    = rest >> 9;
    const int c    = n + i;
    const float* ynr = yn + (size_t)m*CDIM;
    const float* yr  = y  + (size_t)m*CDIM;
    float v = 0.5f * (ynr[c]*inv - yr[c]);
    if (i > 0)     v += 0.25f*(ynr[c-1]*inv - yr[c-1]);
    if (i < LCH-1) v += 0.25f*(ynr[c+1]*inv - yr[c+1]);
    return H[idx]*v;
}

// K3: self-reduce pmaxY -> invY; block-max of t -> pmaxT[bid]. No t stores.
__global__ __launch_bounds__(256) void k3_max(const float* __restrict__ yn,
                                              const float* __restrict__ y,
                                              const float* __restrict__ H,
                                              const float* __restrict__ pmaxY,
                                              float* __restrict__ pmaxT) {
    __shared__ float red[256];
    const float invY = 1.0f / block_max_of(pmaxY, MDIM, red);
    float lmax = -3.4e38f;
    for (int idx = blockIdx.x*blockDim.x + threadIdx.x; idx < NELEM;
         idx += GB3*256)
        lmax = fmaxf(lmax, t_elem(idx, yn, y, H, invY));
    __syncthreads();
    red[threadIdx.x] = lmax; __syncthreads();
    for (int s = 128; s > 0; s >>= 1) {
        if ((int)threadIdx.x < s)
            red[threadIdx.x] = fmaxf(red[threadIdx.x], red[threadIdx.x+s]);
        __syncthreads();
    }
    if (threadIdx.x == 0) pmaxT[blockIdx.x] = red[0];
}

// K4: self-reduce pmaxY, pmaxT -> invY, invT; recompute t, write scaled out.
__global__ __launch_bounds__(256) void k4_out(const float* __restrict__ yn,
                                              const float* __restrict__ y,
                                              const float* __restrict__ H,
                                              const float* __restrict__ pmaxY,
                                              const float* __restrict__ pmaxT,
                                              float* __restrict__ out) {
    __shared__ float red[256];
    const float invY = 1.0f / block_max_of(pmaxY, MDIM, red);
    __syncthreads();
    const float invT = 1.0f / block_max_of(pmaxT, GB3, red);
    for (int idx = blockIdx.x*blockDim.x + threadIdx.x; idx < NELEM;
         idx += GB3*256)
        out[idx] = t_elem(idx, yn, y, H, invY) * invT;
}

extern "C" void kernel_launch(void* const* d_in, const int* in_sizes, int n_in,
                              void* d_out, int out_size, void* d_ws, size_t ws_size,
                              hipStream_t stream) {
    const float* X = (const float*)d_in[0];
    const float* y = (const float*)d_in[1];
    const float* H = (const float*)d_in[2];
    float* out = (float*)d_out;
    float* ws  = (float*)d_ws;

    float* part  = ws + PART_OFF;
    float* yn    = ws + YN_OFF;
    float* pmaxY = ws + PMY_OFF;
    float* pmaxT = ws + PMT_OFF;

    k1_fused<<<NPAIR*NT, 256, 0, stream>>>(X, H, part);     // 4096 blocks
    k2_lite<<<MDIM, 256, 0, stream>>>(part, yn, pmaxY);     // 512 blocks
    k3_max<<<GB3, 256, 0, stream>>>(yn, y, H, pmaxY, pmaxT);
    k4_out<<<GB3, 256, 0, stream>>>(yn, y, H, pmaxY, pmaxT, out);
}

// Round 15
// 100.063 us; speedup vs baseline: 1.1367x; 1.1367x over previous
//
#include <hip/hip_runtime.h>

#define MDIM 512
#define LCH  31
#define CDIM 542   // MD + L - 1
#define INW  1024
#define RS   (INW*LCH)          // floats per input row = 31744
#define NELEM (MDIM*MDIM*LCH)   // 8126464
#define NV4  (NELEM/4)          // 2031616
#define GB3  2048               // k3/k4 grid blocks

#define TNK  32                 // output n-cols per k1 tile
#define NT   16                 // tiles per row (512/32)
#define NPAIR 256               // m-pairs

// ws layout (floats): part[pair][tile][mm][128], yn, pmaxY[512], pmaxT[GB3]
#define PART_OFF 0
#define PART_SZ  (NPAIR*NT*2*128)        // 1048576
#define YN_OFF   (PART_OFF + PART_SZ)
#define PMY_OFF  (YN_OFF + MDIM*CDIM)
#define PMT_OFF  (PMY_OFF + MDIM)

// K1 (r9-verbatim, best measured ~58us): fused bilinear-resize + l-conv +
// H-mult + CASSI diagonal partial sums. Block = (m-pair p, n-tile of 32).
// 6 input rows serve BOTH output rows. 25 KB LDS -> ~6 blocks/CU: cross-block
// TLP is what hides load latency on this part (staging-depth variants r7/r14
// with bigger LDS all regressed). Clamped values only meet zero weights:
//   col -1 / 1024 -> wx0/wx3 = 0 at n = 0/511
//   row -1 / 1024 -> wa0/wb3 = 0 at m = 0/511
__global__ __launch_bounds__(256) void k1_fused(const float* __restrict__ X,
                                                const float* __restrict__ H,
                                                float* __restrict__ part) {
    __shared__ float xv[2][2048];     // vertically-resized flat tiles (16.4 KB)
    __shared__ float xm[2][32][33];   // H*conv tile, padded stride 33 (8.4 KB)

    const int bid = blockIdx.x;
    const int t   = bid & (NT-1);
    const int p   = bid >> 4;
    const int n0  = t * TNK;
    const int m0  = 2*p;
    const int tid = threadIdx.x;
    const int qa  = 1984*t - 32;      // float4-aligned staged-q origin

    const float* rp0 = X + (size_t)max(4*p - 1, 0) * RS;
    const float* rp1 = X + (size_t)(4*p    ) * RS;
    const float* rp2 = X + (size_t)(4*p + 1) * RS;
    const float* rp3 = X + (size_t)(4*p + 2) * RS;
    const float* rp4 = X + (size_t)(4*p + 3) * RS;
    const float* rp5 = X + (size_t)min(4*p + 4, INW-1) * RS;

    float wa0=0.125f, wa1=0.375f, wa2=0.375f, wa3=0.125f;   // m = m0
    if (m0 == 0) {
        const float s = 1.0f/0.875f;
        wa0 = 0.f; wa1 = 0.375f*s; wa2 = 0.375f*s; wa3 = 0.125f*s;
    }
    float wb0=0.125f, wb1=0.375f, wb2=0.375f, wb3=0.125f;   // m = m0+1
    if (m0 + 1 == MDIM-1) {
        const float s = 1.0f/0.875f;
        wb0 = 0.125f*s; wb1 = 0.375f*s; wb2 = 0.375f*s; wb3 = 0.f;
    }

    #pragma unroll
    for (int j = 0; j < 2; ++j) {
        const int u = tid + 256*j;
        int q = qa + 4*u;
        q = min(max(q, 0), RS - 4);   // clamp -> zero-weight taps only
        const float4 r0 = *(const float4*)(rp0 + q);
        const float4 r1 = *(const float4*)(rp1 + q);
        const float4 r2 = *(const float4*)(rp2 + q);
        const float4 r3 = *(const float4*)(rp3 + q);
        const float4 r4 = *(const float4*)(rp4 + q);
        const float4 r5 = *(const float4*)(rp5 + q);
        float4 va, vb;
        va.x = fmaf(wa0,r0.x, fmaf(wa1,r1.x, fmaf(wa2,r2.x, wa3*r3.x)));
        va.y = fmaf(wa0,r0.y, fmaf(wa1,r1.y, fmaf(wa2,r2.y, wa3*r3.y)));
        va.z = fmaf(wa0,r0.z, fmaf(wa1,r1.z, fmaf(wa2,r2.z, wa3*r3.z)));
        va.w = fmaf(wa0,r0.w, fmaf(wa1,r1.w, fmaf(wa2,r2.w, wa3*r3.w)));
        vb.x = fmaf(wb0,r2.x, fmaf(wb1,r3.x, fmaf(wb2,r4.x, wb3*r5.x)));
        vb.y = fmaf(wb0,r2.y, fmaf(wb1,r3.y, fmaf(wb2,r4.y, wb3*r5.y)));
        vb.z = fmaf(wb0,r2.z, fmaf(wb1,r3.z, fmaf(wb2,r4.z, wb3*r5.z)));
        vb.w = fmaf(wb0,r2.w, fmaf(wb1,r3.w, fmaf(wb2,r4.w, wb3*r5.w)));
        *(float4*)&xv[0][4*u] = va;
        *(float4*)&xv[1][4*u] = vb;
    }
    __syncthreads();

    // ---- phase 2: l-conv + horizontal 4-tap + H multiply -> xm tile ----
    const size_t hbase = ((size_t)m0*MDIM + n0)*LCH;
    for (int idx = tid; idx < 2*TNK*LCH; idx += 256) {   // 1984
        const int mm = idx >= TNK*LCH;
        const int r2 = mm ? idx - TNK*LCH : idx;
        const int nl = r2 / 31;
        const int l  = r2 - nl*31;
        const int n  = n0 + nl;
        float wx0=0.125f, wx1=0.375f, wx2=0.375f, wx3=0.125f;
        if (n == 0)      wx0 = 0.f;
        if (n == MDIM-1) wx3 = 0.f;
        if (n == 0 || n == MDIM-1) {
            const float s = 1.0f/0.875f;
            wx0*=s; wx1*=s; wx2*=s; wx3*=s;
        }
        const float wb4[4] = {wx0, wx1, wx2, wx3};
        const float* xvm = xv[mm];
        const int ib = 2*nl*31 + l + 1;
        float acc = 0.f;
        #pragma unroll
        for (int b = 0; b < 4; ++b) {
            const float* q = xvm + ib + 31*b;
            float c = 0.5f*q[0];
            if (l > 0)  c += 0.25f*q[-1];
            if (l < 30) c += 0.25f*q[1];
            acc = fmaf(wb4[b], c, acc);
        }
        xm[mm][nl][l] = acc * H[hbase + (size_t)mm*(MDIM*LCH) + r2];
    }
    __syncthreads();

    // ---- phase 3: diagonal partials: cl = c - n0 in [0,62), 2 halves ----
    if (tid < 248) {
        const int mm = tid >= 124;
        const int r3 = mm ? tid - 124 : tid;
        const int h  = r3 >= 62;
        const int cl = h ? r3 - 62 : r3;
        const int ilo = max(0, cl - (TNK-1));
        const int ihi = min(30, cl);
        const int mid = (ilo + ihi + 1) >> 1;
        const int lo  = h ? mid : ilo;
        const int hi  = h ? ihi : mid - 1;
        float s = 0.f;
        for (int i = lo; i <= hi; ++i)
            s += xm[mm][cl - i][i];          // stride-33 -> conflict-free
        part[(((size_t)p*NT + t)*2 + mm)*128 + h*64 + cl] = s;
    }
}

// K2_lite (r9-verbatim): yn[m][c] from tile partials; per-row max.
__global__ __launch_bounds__(256) void k2_lite(const float* __restrict__ part,
                                               float* __restrict__ yn,
                                               float* __restrict__ pmaxY) {
    const int m = blockIdx.x;
    const int p = m >> 1, mm = m & 1;
    float lmax = -3.4e38f;
    for (int c = threadIdx.x; c < CDIM; c += 256) {
        float s = 0.f;
        const int tlo = max(0, (c - 30) >> 5);
        const int thi = min(NT - 1, c >> 5);
        for (int t = tlo; t <= thi; ++t) {
            const int cl = c - TNK*t;               // in [0,62)
            const float* pp = part + (((size_t)p*NT + t)*2 + mm)*128;
            s += pp[cl] + pp[64 + cl];
        }
        yn[m*CDIM + c] = s;
        lmax = fmaxf(lmax, s);
    }
    __shared__ float red[256];
    red[threadIdx.x] = lmax; __syncthreads();
    for (int s = 128; s > 0; s >>= 1) {
        if ((int)threadIdx.x < s)
            red[threadIdx.x] = fmaxf(red[threadIdx.x], red[threadIdx.x+s]);
        __syncthreads();
    }
    if (threadIdx.x == 0) pmaxY[m] = red[0];
}

// block-uniform reduction of an L2-resident partial-max array (deterministic:
// every block computes the identical max; order-free).
__device__ __forceinline__ float block_max_of(const float* __restrict__ arr,
                                              int n, float* red) {
    float lm = -3.4e38f;
    for (int i = threadIdx.x; i < n; i += 256)
        lm = fmaxf(lm, arr[i]);
    __syncthreads();
    red[threadIdx.x] = lm; __syncthreads();
    for (int s = 128; s > 0; s >>= 1) {
        if ((int)threadIdx.x < s)
            red[threadIdx.x] = fmaxf(red[threadIdx.x], red[threadIdx.x+s]);
        __syncthreads();
    }
    return red[0];
}

// 4 consecutive t-values sharing one float4 H load; (i,n,m) carried
// incrementally. r(c) = yn[m][c]*invY - y[m][c].
template <bool STORE>
__device__ __forceinline__ float t_quad(int v4,
                                        const float* __restrict__ yn,
                                        const float* __restrict__ y,
                                        const float* __restrict__ H,
                                        float invY, float invT,
                                        float* __restrict__ out) {
    const int idx = v4 << 2;
    const float4 h = *(const float4*)(H + idx);
    const float hv[4] = {h.x, h.y, h.z, h.w};
    int i    = idx % LCH;
    int rest = idx / LCH;
    int n    = rest & (MDIM-1);
    int m    = rest >> 9;
    float tv[4];
    float lmax = -3.4e38f;
    #pragma unroll
    for (int e = 0; e < 4; ++e) {
        const float* ynr = yn + m*CDIM;
        const float* yr  = y  + m*CDIM;
        const int c = n + i;
        float v = 0.5f * (ynr[c]*invY - yr[c]);
        if (i > 0)       v += 0.25f*(ynr[c-1]*invY - yr[c-1]);
        if (i < LCH-1)   v += 0.25f*(ynr[c+1]*invY - yr[c+1]);
        tv[e] = hv[e]*v;
        lmax = fmaxf(lmax, tv[e]);
        if (++i == LCH) { i = 0; if (++n == MDIM) { n = 0; ++m; } }
    }
    if (STORE) {
        float4 o; o.x = tv[0]*invT; o.y = tv[1]*invT;
        o.z = tv[2]*invT; o.w = tv[3]*invT;
        *(float4*)(out + idx) = o;
    }
    return lmax;
}

// K3: self-reduce pmaxY -> invY; float4-H block-max of t -> pmaxT[bid].
__global__ __launch_bounds__(256) void k3_max(const float* __restrict__ yn,
                                              const float* __restrict__ y,
                                              const float* __restrict__ H,
                                              const float* __restrict__ pmaxY,
                                              float* __restrict__ pmaxT) {
    __shared__ float red[256];
    const float invY = 1.0f / block_max_of(pmaxY, MDIM, red);
    float lmax = -3.4e38f;
    for (int v4 = blockIdx.x*blockDim.x + threadIdx.x; v4 < NV4;
         v4 += GB3*256)
        lmax = fmaxf(lmax, t_quad<false>(v4, yn, y, H, invY, 0.f, nullptr));
    __syncthreads();
    red[threadIdx.x] = lmax; __syncthreads();
    for (int s = 128; s > 0; s >>= 1) {
        if ((int)threadIdx.x < s)
            red[threadIdx.x] = fmaxf(red[threadIdx.x], red[threadIdx.x+s]);
        __syncthreads();
    }
    if (threadIdx.x == 0) pmaxT[blockIdx.x] = red[0];
}

// K4: self-reduce both maxes; recompute t, write scaled out as float4.
__global__ __launch_bounds__(256) void k4_out(const float* __restrict__ yn,
                                              const float* __restrict__ y,
                                              const float* __restrict__ H,
                                              const float* __restrict__ pmaxY,
                                              const float* __restrict__ pmaxT,
                                              float* __restrict__ out) {
    __shared__ float red[256];
    const float invY = 1.0f / block_max_of(pmaxY, MDIM, red);
    __syncthreads();
    const float invT = 1.0f / block_max_of(pmaxT, GB3, red);
    for (int v4 = blockIdx.x*blockDim.x + threadIdx.x; v4 < NV4;
         v4 += GB3*256)
        t_quad<true>(v4, yn, y, H, invY, invT, out);
}

extern "C" void kernel_launch(void* const* d_in, const int* in_sizes, int n_in,
                              void* d_out, int out_size, void* d_ws, size_t ws_size,
                              hipStream_t stream) {
    const float* X = (const float*)d_in[0];
    const float* y = (const float*)d_in[1];
    const float* H = (const float*)d_in[2];
    float* out = (float*)d_out;
    float* ws  = (float*)d_ws;

    float* part  = ws + PART_OFF;
    float* yn    = ws + YN_OFF;
    float* pmaxY = ws + PMY_OFF;
    float* pmaxT = ws + PMT_OFF;

    k1_fused<<<NPAIR*NT, 256, 0, stream>>>(X, H, part);     // 4096 blocks
    k2_lite<<<MDIM, 256, 0, stream>>>(part, yn, pmaxY);     // 512 blocks
    k3_max<<<GB3, 256, 0, stream>>>(yn, y, H, pmaxY, pmaxT);
    k4_out<<<GB3, 256, 0, stream>>>(yn, y, H, pmaxY, pmaxT, out);
}

// Round 16
// 86.724 us; speedup vs baseline: 1.3116x; 1.1538x over previous
//
#include <hip/hip_runtime.h>

#define MDIM 512
#define LCH  31
#define CDIM 542   // MD + L - 1
#define INW  1024
#define RS   (INW*LCH)          // floats per input row = 31744
#define NELEM (MDIM*MDIM*LCH)   // 8126464
#define GB3  2048               // k3/k4 grid blocks

#define TNK  16                 // output n-cols per k1 tile (halved vs r9)
#define NT   32                 // tiles per row (512/16)
#define NPAIR 256               // m-pairs
#define SEGF 1056               // staged floats per sub-tile (33 cols x 31 + pad)
#define NF4  264                // float4s per sub-tile
#define DIAG 46                 // distinct c per tile: TNK + LCH - 1

// ws layout (floats): part[pair][tile][mm][128], yn, pmaxY[512], pmaxT[GB3], scl[2]
#define PART_OFF 0
#define PART_SZ  (NPAIR*NT*2*128)        // 2097152
#define YN_OFF   (PART_OFF + PART_SZ)
#define PMY_OFF  (YN_OFF + MDIM*CDIM)
#define PMT_OFF  (PMY_OFF + MDIM)
#define SCL_OFF  (PMT_OFF + GB3)

// K1: r9 math at half tile width. Block = (m-pair p, n-tile of 16).
// 12.7 KB LDS -> 8 blocks/CU (wave-capped) vs r9's 25 KB/~5: doubles the
// number of independently-staggered blocks per CU so some block is always
// in its load phase (theory: barrier-phased blocks in lockstep leave the
// memory pipe idle half the time; k1 delivers only ~12.6 GB/s/CU vs the
// 24.6 GB/s/CU copy ceiling). Clamped values only meet zero weights:
//   col -1 / 1024 -> wx0/wx3 = 0 at n = 0/511
//   row -1 / 1024 -> wa0/wb3 = 0 at m = 0/511
__global__ __launch_bounds__(256) void k1_fused(const float* __restrict__ X,
                                                const float* __restrict__ H,
                                                float* __restrict__ part) {
    __shared__ float xv[2][SEGF];     // 8.4 KB vertically-resized tiles
    __shared__ float xm[2][TNK][33];  // 4.3 KB H*conv tiles, padded

    const int bid = blockIdx.x;
    const int t   = bid & (NT-1);
    const int p   = bid >> 5;
    const int n0  = t * TNK;
    const int m0  = 2*p;
    const int tid = threadIdx.x;
    const int qa  = 992*t - 32;       // float4-aligned staged-q origin

    const float* rp0 = X + (size_t)max(4*p - 1, 0) * RS;
    const float* rp1 = X + (size_t)(4*p    ) * RS;
    const float* rp2 = X + (size_t)(4*p + 1) * RS;
    const float* rp3 = X + (size_t)(4*p + 2) * RS;
    const float* rp4 = X + (size_t)(4*p + 3) * RS;
    const float* rp5 = X + (size_t)min(4*p + 4, INW-1) * RS;

    float wa0=0.125f, wa1=0.375f, wa2=0.375f, wa3=0.125f;   // m = m0
    if (m0 == 0) {
        const float s = 1.0f/0.875f;
        wa0 = 0.f; wa1 = 0.375f*s; wa2 = 0.375f*s; wa3 = 0.125f*s;
    }
    float wb0=0.125f, wb1=0.375f, wb2=0.375f, wb3=0.125f;   // m = m0+1
    if (m0 + 1 == MDIM-1) {
        const float s = 1.0f/0.875f;
        wb0 = 0.125f*s; wb1 = 0.375f*s; wb2 = 0.375f*s; wb3 = 0.f;
    }

    // ---- phase 1: 6-row streams, vertical 4-tap for both m ----
    for (int u = tid; u < NF4; u += 256) {
        int q = qa + 4*u;
        q = min(max(q, 0), RS - 4);   // clamp -> zero-weight taps only
        const float4 r0 = *(const float4*)(rp0 + q);
        const float4 r1 = *(const float4*)(rp1 + q);
        const float4 r2 = *(const float4*)(rp2 + q);
        const float4 r3 = *(const float4*)(rp3 + q);
        const float4 r4 = *(const float4*)(rp4 + q);
        const float4 r5 = *(const float4*)(rp5 + q);
        float4 va, vb;
        va.x = fmaf(wa0,r0.x, fmaf(wa1,r1.x, fmaf(wa2,r2.x, wa3*r3.x)));
        va.y = fmaf(wa0,r0.y, fmaf(wa1,r1.y, fmaf(wa2,r2.y, wa3*r3.y)));
        va.z = fmaf(wa0,r0.z, fmaf(wa1,r1.z, fmaf(wa2,r2.z, wa3*r3.z)));
        va.w = fmaf(wa0,r0.w, fmaf(wa1,r1.w, fmaf(wa2,r2.w, wa3*r3.w)));
        vb.x = fmaf(wb0,r2.x, fmaf(wb1,r3.x, fmaf(wb2,r4.x, wb3*r5.x)));
        vb.y = fmaf(wb0,r2.y, fmaf(wb1,r3.y, fmaf(wb2,r4.y, wb3*r5.y)));
        vb.z = fmaf(wb0,r2.z, fmaf(wb1,r3.z, fmaf(wb2,r4.z, wb3*r5.z)));
        vb.w = fmaf(wb0,r2.w, fmaf(wb1,r3.w, fmaf(wb2,r4.w, wb3*r5.w)));
        *(float4*)&xv[0][4*u] = va;
        *(float4*)&xv[1][4*u] = vb;
    }
    __syncthreads();

    // ---- phase 2: l-conv + horizontal 4-tap + H multiply -> xm tile ----
    // xv[mm][i] holds vert(q = qa + i); tap (col = 2n-1+b, l) at
    // i = 2*nl*31 + 31*b + l + 1 (max 1054 < 1056).
    const size_t hbase = ((size_t)m0*MDIM + n0)*LCH;
    for (int idx = tid; idx < 2*TNK*LCH; idx += 256) {   // 992
        const int mm = idx >= TNK*LCH;
        const int r2 = mm ? idx - TNK*LCH : idx;
        const int nl = r2 / 31;
        const int l  = r2 - nl*31;
        const int n  = n0 + nl;
        float wx0=0.125f, wx1=0.375f, wx2=0.375f, wx3=0.125f;
        if (n == 0)      wx0 = 0.f;
        if (n == MDIM-1) wx3 = 0.f;
        if (n == 0 || n == MDIM-1) {
            const float s = 1.0f/0.875f;
            wx0*=s; wx1*=s; wx2*=s; wx3*=s;
        }
        const float wb4[4] = {wx0, wx1, wx2, wx3};
        const float* xvm = xv[mm];
        const int ib = 2*nl*31 + l + 1;
        float acc = 0.f;
        #pragma unroll
        for (int b = 0; b < 4; ++b) {
            const float* q = xvm + ib + 31*b;
            float c = 0.5f*q[0];
            if (l > 0)  c += 0.25f*q[-1];
            if (l < 30) c += 0.25f*q[1];
            acc = fmaf(wb4[b], c, acc);
        }
        xm[mm][nl][l] = acc * H[hbase + (size_t)mm*(MDIM*LCH) + r2];
    }
    __syncthreads();

    // ---- phase 3: diagonal partials: cl = c - n0 in [0,46), 2 halves ----
    if (tid < 2*2*DIAG) {                 // 184
        const int mm = tid >= 2*DIAG;
        const int r3 = mm ? tid - 2*DIAG : tid;
        const int h  = r3 >= DIAG;
        const int cl = h ? r3 - DIAG : r3;
        const int ilo = max(0, cl - (TNK-1));
        const int ihi = min(30, cl);
        const int mid = (ilo + ihi + 1) >> 1;
        const int lo  = h ? mid : ilo;
        const int hi  = h ? ihi : mid - 1;
        float s = 0.f;
        for (int i = lo; i <= hi; ++i)
            s += xm[mm][cl - i][i];          // stride-33 -> conflict-free
        part[(((size_t)p*NT + t)*2 + mm)*128 + h*64 + cl] = s;
    }
}

// K2_lite: yn[m][c] from tile partials (<=3 tiles x 2 halves); per-row max.
__global__ __launch_bounds__(256) void k2_lite(const float* __restrict__ part,
                                               float* __restrict__ yn,
                                               float* __restrict__ pmaxY) {
    const int m = blockIdx.x;
    const int p = m >> 1, mm = m & 1;
    float lmax = -3.4e38f;
    for (int c = threadIdx.x; c < CDIM; c += 256) {
        float s = 0.f;
        const int tlo = max(0, (c - 30) >> 4);      // ceil((c-45)/16)
        const int thi = min(NT - 1, c >> 4);
        for (int t = tlo; t <= thi; ++t) {
            const int cl = c - TNK*t;               // in [0,46)
            const float* pp = part + (((size_t)p*NT + t)*2 + mm)*128;
            s += pp[cl] + pp[64 + cl];
        }
        yn[m*CDIM + c] = s;
        lmax = fmaxf(lmax, s);
    }
    __shared__ float red[256];
    red[threadIdx.x] = lmax; __syncthreads();
    for (int s = 128; s > 0; s >>= 1) {
        if ((int)threadIdx.x < s)
            red[threadIdx.x] = fmaxf(red[threadIdx.x], red[threadIdx.x+s]);
        __syncthreads();
    }
    if (threadIdx.x == 0) pmaxY[m] = red[0];
}

// Reduce n partial maxes -> out_inv[0] = 1/max. Single block, deterministic.
__global__ __launch_bounds__(256) void kmax_reduce(const float* __restrict__ pmax,
                                                   int n,
                                                   float* __restrict__ out_inv) {
    __shared__ float red[256];
    float lmax = -3.4e38f;
    for (int i = threadIdx.x; i < n; i += 256)
        lmax = fmaxf(lmax, pmax[i]);
    red[threadIdx.x] = lmax; __syncthreads();
    for (int s = 128; s > 0; s >>= 1) {
        if ((int)threadIdx.x < s)
            red[threadIdx.x] = fmaxf(red[threadIdx.x], red[threadIdx.x+s]);
        __syncthreads();
    }
    if (threadIdx.x == 0) out_inv[0] = 1.0f / red[0];
}

// t(idx) = H[idx] * conv_i(yn/My - y at c=n+i)
__device__ __forceinline__ float t_elem(int idx,
                                        const float* __restrict__ yn,
                                        const float* __restrict__ y,
                                        const float* __restrict__ H,
                                        float inv) {
    const int i    = idx % LCH;
    const int rest = idx / LCH;
    const int n    = rest & (MDIM-1);
    const int m    = rest >> 9;
    const int c    = n + i;
    const float* ynr = yn + (size_t)m*CDIM;
    const float* yr  = y  + (size_t)m*CDIM;
    float v = 0.5f * (ynr[c]*inv - yr[c]);
    if (i > 0)     v += 0.25f*(ynr[c-1]*inv - yr[c-1]);
    if (i < LCH-1) v += 0.25f*(ynr[c+1]*inv - yr[c+1]);
    return H[idx]*v;
}

// K3: block-max of t over grid-stride range -> pmaxT[bid]. No stores of t.
__global__ __launch_bounds__(256) void k3_max(const float* __restrict__ yn,
                                              const float* __restrict__ y,
                                              const float* __restrict__ H,
                                              const float* __restrict__ scl,
                                              float* __restrict__ pmaxT) {
    const float inv = scl[0];
    float lmax = -3.4e38f;
    for (int idx = blockIdx.x*blockDim.x + threadIdx.x; idx < NELEM;
         idx += GB3*256)
        lmax = fmaxf(lmax, t_elem(idx, yn, y, H, inv));
    __shared__ float red[256];
    red[threadIdx.x] = lmax; __syncthreads();
    for (int s = 128; s > 0; s >>= 1) {
        if ((int)threadIdx.x < s)
            red[threadIdx.x] = fmaxf(red[threadIdx.x], red[threadIdx.x+s]);
        __syncthreads();
    }
    if (threadIdx.x == 0) pmaxT[blockIdx.x] = red[0];
}

// K4: recompute t, scale by 1/maxT, write out (coalesced, single pass).
__global__ __launch_bounds__(256) void k4_out(const float* __restrict__ yn,
                                              const float* __restrict__ y,
                                              const float* __restrict__ H,
                                              const float* __restrict__ scl,
                                              float* __restrict__ out) {
    const float inv  = scl[0];
    const float invT = scl[1];
    for (int idx = blockIdx.x*blockDim.x + threadIdx.x; idx < NELEM;
         idx += GB3*256)
        out[idx] = t_elem(idx, yn, y, H, inv) * invT;
}

extern "C" void kernel_launch(void* const* d_in, const int* in_sizes, int n_in,
                              void* d_out, int out_size, void* d_ws, size_t ws_size,
                              hipStream_t stream) {
    const float* X = (const float*)d_in[0];
    const float* y = (const float*)d_in[1];
    const float* H = (const float*)d_in[2];
    float* out = (float*)d_out;
    float* ws  = (float*)d_ws;

    float* part  = ws + PART_OFF;
    float* yn    = ws + YN_OFF;
    float* pmaxY = ws + PMY_OFF;
    float* pmaxT = ws + PMT_OFF;
    float* scl   = ws + SCL_OFF;   // [0]=1/maxY, [1]=1/maxT

    k1_fused<<<NPAIR*NT, 256, 0, stream>>>(X, H, part);     // 8192 blocks
    k2_lite<<<MDIM, 256, 0, stream>>>(part, yn, pmaxY);     // 512 blocks
    kmax_reduce<<<1, 256, 0, stream>>>(pmaxY, MDIM, scl);
    k3_max<<<GB3, 256, 0, stream>>>(yn, y, H, scl, pmaxT);
    kmax_reduce<<<1, 256, 0, stream>>>(pmaxT, GB3, scl + 1);
    k4_out<<<GB3, 256, 0, stream>>>(yn, y, H, scl, out);
}